// Round 3
// baseline (8141.962 us; speedup 1.0000x reference)
//
#include <hip/hip_runtime.h>

#define U_N 100000
#define I_N 50000
#define D_N 64
#define B_N 4
#define E_N 2000000

#define EDGES   (B_N * E_N)          // 8,000,000 per side
#define TOT     (2 * EDGES)          // 16,000,000 edge-entries
#define BU      (B_N * U_N)          // 400,000 user bins
#define BI      (B_N * I_N)          // 200,000 item bins
#define NB      (BU + BI)            // 600,000 bins total
#define G_BINS  128                  // bins per chunk (LDS tile = 128x64 f32 = 32 KB)
#define NSC     ((NB + G_BINS - 1) / G_BINS)   // 4688 chunks
#define NSC_U   (BU / G_BINS)        // 3125 (exact: 400000/128) user-side chunks

// ---------------------------------------------------------------------------
// Pass 1: per-chunk histogram (LDS-staged; 4688 counters = 18.75 KB LDS).
// ---------------------------------------------------------------------------
__global__ __launch_bounds__(256) void chist_kernel(const int* __restrict__ rows,
                                                    const int* __restrict__ cols,
                                                    int* __restrict__ cnt) {
    __shared__ int h[NSC];
    for (int i = threadIdx.x; i < NSC; i += 256) h[i] = 0;
    __syncthreads();
    int stride = gridDim.x * 256;
    for (int i = blockIdx.x * 256 + threadIdx.x; i < TOT; i += stride) {
        int bin;
        if (i < EDGES) {
            int b = i / E_N;
            bin = b * U_N + rows[i];
        } else {
            int e = i - EDGES;
            int b = e / E_N;
            bin = BU + b * I_N + cols[e];
        }
        atomicAdd(&h[bin >> 7], 1);
    }
    __syncthreads();
    for (int i = threadIdx.x; i < NSC; i += 256) {
        int v = h[i];
        if (v) atomicAdd(&cnt[i], v);
    }
}

// ---------------------------------------------------------------------------
// Pass 2: exclusive scan over 4688 chunk counts (single block).
// ---------------------------------------------------------------------------
#define SC_PER_T 19                  // 256*19 = 4864 >= 4688
__global__ __launch_bounds__(256) void cscan_kernel(const int* __restrict__ cnt,
                                                    int* __restrict__ off,
                                                    int* __restrict__ cur) {
    int t = threadIdx.x;
    int loc[SC_PER_T];
    int s = 0;
#pragma unroll
    for (int j = 0; j < SC_PER_T; ++j) {
        int idx = t * SC_PER_T + j;
        int c = (idx < NSC) ? cnt[idx] : 0;
        loc[j] = s; s += c;
    }
    __shared__ int sm[256];
    int mine = s;
    sm[t] = s; __syncthreads();
    for (int o = 1; o < 256; o <<= 1) {
        int a = (t >= o) ? sm[t - o] : 0;
        __syncthreads();
        sm[t] += a;
        __syncthreads();
    }
    int pre = sm[t] - mine;
#pragma unroll
    for (int j = 0; j < SC_PER_T; ++j) {
        int idx = t * SC_PER_T + j;
        if (idx < NSC) { int o2 = pre + loc[j]; off[idx] = o2; cur[idx] = o2; }
    }
}

// ---------------------------------------------------------------------------
// Pass 3: coarse partition. Scattered 4B stores land in only 4688 active
// regions (~300 KB of active cachelines) -> L2 absorbs, lines fill fully.
// Payload: local_bin(7b)<<23 | b(2b)<<21 | edge_local(21b).
// ---------------------------------------------------------------------------
__global__ __launch_bounds__(256) void cpart_kernel(const int* __restrict__ rows,
                                                    const int* __restrict__ cols,
                                                    int* __restrict__ cur,
                                                    unsigned int* __restrict__ pay) {
    int i = blockIdx.x * 256 + threadIdx.x;
    if (i >= TOT) return;
    int bin, b, el;
    if (i < EDGES) {
        b = i / E_N; el = i - b * E_N;
        bin = b * U_N + rows[i];
    } else {
        int e = i - EDGES;
        b = e / E_N; el = e - b * E_N;
        bin = BU + b * I_N + cols[e];
    }
    unsigned int p = ((unsigned int)(bin & 127) << 23) |
                     ((unsigned int)b << 21) | (unsigned int)el;
    int pos = atomicAdd(&cur[bin >> 7], 1);
    pay[pos] = p;
}

// ---------------------------------------------------------------------------
// Pass 4: per-chunk accumulate into a 128x64 f32 LDS tile.
// One block per chunk; wave-per-entry; lane = dim. Broadcasts via v_readlane
// (scalar pipe) to keep the LDS pipe for ds_add_f32 only.
// ---------------------------------------------------------------------------
__global__ __launch_bounds__(256) void accum_kernel(
        const float* __restrict__ user_emb,
        const float* __restrict__ item_emb,
        const int* __restrict__ rows,
        const int* __restrict__ cols,
        const float* __restrict__ vals,
        const int* __restrict__ off,
        const int* __restrict__ cnt,
        const unsigned int* __restrict__ pay,
        float* __restrict__ stack_u,
        float* __restrict__ stack_i) {
    int g = blockIdx.x;
    bool user_side = (g < NSC_U);
    const float* emb    = user_side ? item_emb : user_emb;
    const int*   srcidx = user_side ? cols     : rows;
    int start = off[g];
    int n     = cnt[g];

    __shared__ float acc[G_BINS * 64];
    for (int i = threadIdx.x; i < G_BINS * 64; i += 256) acc[i] = 0.f;
    __syncthreads();

    int w = threadIdx.x >> 6, lane = threadIdx.x & 63;
    for (int j0 = w * 64; j0 < n; j0 += 256) {
        int m = n - j0; if (m > 64) m = 64;
        unsigned int pl = 0; float vf = 0.f; int sv = 0;
        if (lane < m) {
            pl = pay[start + j0 + lane];
            int b = (int)((pl >> 21) & 3u);
            int e = b * E_N + (int)(pl & 0x1FFFFFu);
            vf = vals[e];
            sv = srcidx[e];
        }
        if (m == 64) {
#pragma unroll 4
            for (int k = 0; k < 64; ++k) {
                unsigned int p = (unsigned int)__builtin_amdgcn_readlane((int)pl, k);
                int   local = (int)(p >> 23);
                int   s = __builtin_amdgcn_readlane(sv, k);
                float v = __int_as_float(__builtin_amdgcn_readlane(__float_as_int(vf), k));
                float x = emb[s * 64 + lane];
                atomicAdd(&acc[local * 64 + lane], v * x);
            }
        } else {
            for (int k = 0; k < m; ++k) {
                unsigned int p = (unsigned int)__builtin_amdgcn_readlane((int)pl, k);
                int   local = (int)(p >> 23);
                int   s = __builtin_amdgcn_readlane(sv, k);
                float v = __int_as_float(__builtin_amdgcn_readlane(__float_as_int(vf), k));
                float x = emb[s * 64 + lane];
                atomicAdd(&acc[local * 64 + lane], v * x);
            }
        }
    }
    __syncthreads();

    long long bin0 = (long long)g << 7;
    if (user_side) {
        float* dst = stack_u + bin0 * 64;
        for (int i = threadIdx.x; i < G_BINS * 64; i += 256) dst[i] = acc[i];
    } else {
        long long r0 = bin0 - BU;
        float* dst = stack_i + r0 * 64;
        int lim = (int)(((long long)BI - r0) * 64);   // guard phantom tail bins
        if (lim > G_BINS * 64) lim = G_BINS * 64;
        for (int i = threadIdx.x; i < lim; i += 256) dst[i] = acc[i];
    }
}

// ---------------------------------------------------------------------------
// Fallback (round-1): atomic scatter, used only if ws_size is too small.
// ---------------------------------------------------------------------------
__global__ void scatter_atomic_kernel(const float* __restrict__ user_emb,
                                      const float* __restrict__ item_emb,
                                      const int* __restrict__ rows,
                                      const int* __restrict__ cols,
                                      const float* __restrict__ vals,
                                      float* __restrict__ stack_u,
                                      float* __restrict__ stack_i) {
    long long tid = (long long)blockIdx.x * blockDim.x + threadIdx.x;
    long long e  = tid >> 4;
    int lane = (int)(tid & 15);
    if (e >= (long long)EDGES) return;
    int b = (int)(e / E_N);
    int r = rows[e];
    int c = cols[e];
    float v = vals[e];
    const float4* irow = (const float4*)(item_emb + (long long)c * D_N);
    const float4* urow = (const float4*)(user_emb + (long long)r * D_N);
    float4 iv = irow[lane];
    float4 uv = urow[lane];
    float* du = stack_u + ((long long)b * U_N + r) * D_N + lane * 4;
    float* di = stack_i + ((long long)b * I_N + c) * D_N + lane * 4;
    atomicAdd(du + 0, v * iv.x);
    atomicAdd(du + 1, v * iv.y);
    atomicAdd(du + 2, v * iv.z);
    atomicAdd(du + 3, v * iv.w);
    atomicAdd(di + 0, v * uv.x);
    atomicAdd(di + 1, v * uv.y);
    atomicAdd(di + 2, v * uv.z);
    atomicAdd(di + 3, v * uv.w);
}

// ---------------------------------------------------------------------------
// Phase 2: per-row dense transform + sigmoid, in place (unchanged).
// ---------------------------------------------------------------------------
template <int NROWS>
__global__ __launch_bounds__(64) void transform_kernel(
        float* __restrict__ stack,       // [B, NROWS, D] in/out
        const float* __restrict__ W,     // [D, D]
        float* __restrict__ mean_out) {  // [NROWS, D]
    const int row = blockIdx.x;
    const int j   = threadIdx.x;

    __shared__ float xs[B_N][D_N];
#pragma unroll
    for (int b = 0; b < B_N; ++b)
        xs[b][j] = stack[((long long)b * NROWS + row) * D_N + j];
    __syncthreads();

    float acc[B_N] = {0.f, 0.f, 0.f, 0.f};
#pragma unroll 8
    for (int d = 0; d < D_N; ++d) {
        float w = W[d * D_N + j];
#pragma unroll
        for (int b = 0; b < B_N; ++b)
            acc[b] += xs[b][d] * w;
    }

    float m = 0.25f * (acc[0] + acc[1] + acc[2] + acc[3]);
#pragma unroll
    for (int b = 0; b < B_N; ++b)
        stack[((long long)b * NROWS + row) * D_N + j] =
            1.0f / (1.0f + __expf(-acc[b]));
    mean_out[(long long)row * D_N + j] = 1.0f / (1.0f + __expf(-m));
}

// ---------------------------------------------------------------------------
extern "C" void kernel_launch(void* const* d_in, const int* in_sizes, int n_in,
                              void* d_out, int out_size, void* d_ws, size_t ws_size,
                              hipStream_t stream) {
    const float* user_emb = (const float*)d_in[0];
    const float* item_emb = (const float*)d_in[1];
    const int*   rows     = (const int*)  d_in[2];
    const int*   cols     = (const int*)  d_in[3];
    const float* vals     = (const float*)d_in[4];
    const float* u_w      = (const float*)d_in[5];
    const float* i_w      = (const float*)d_in[6];

    float* out = (float*)d_out;
    float* user_mean = out;
    float* item_mean = out + (long long)U_N * D_N;
    float* stack_u   = item_mean + (long long)I_N * D_N;     // [B,U,D] out
    float* stack_i   = stack_u + (long long)B_N * U_N * D_N; // [B,I,D] out

    size_t needed = ((size_t)3 * NSC + (size_t)TOT) * sizeof(int);  // ~64.06 MB
    if (ws_size >= needed) {
        int* cnt = (int*)d_ws;
        int* off = cnt + NSC;
        int* cur = off + NSC;
        unsigned int* pay = (unsigned int*)(cur + NSC);

        hipMemsetAsync(cnt, 0, (size_t)NSC * sizeof(int), stream);

        chist_kernel<<<512, 256, 0, stream>>>(rows, cols, cnt);
        cscan_kernel<<<1, 256, 0, stream>>>(cnt, off, cur);
        cpart_kernel<<<TOT / 256, 256, 0, stream>>>(rows, cols, cur, pay);
        accum_kernel<<<NSC, 256, 0, stream>>>(user_emb, item_emb, rows, cols,
                                              vals, off, cnt, pay,
                                              stack_u, stack_i);
    } else {
        size_t stack_bytes = sizeof(float) * (size_t)B_N * (U_N + I_N) * D_N;
        hipMemsetAsync(stack_u, 0, stack_bytes, stream);
        long long nthreads = (long long)EDGES * 16;
        int block = 256;
        int nblocks = (int)((nthreads + block - 1) / block);
        scatter_atomic_kernel<<<nblocks, block, 0, stream>>>(
            user_emb, item_emb, rows, cols, vals, stack_u, stack_i);
    }

    transform_kernel<U_N><<<U_N, 64, 0, stream>>>(stack_u, u_w, user_mean);
    transform_kernel<I_N><<<I_N, 64, 0, stream>>>(stack_i, i_w, item_mean);
}

// Round 4
// 6907.771 us; speedup vs baseline: 1.1787x; 1.1787x over previous
//
#include <hip/hip_runtime.h>

#define U_N 100000
#define I_N 50000
#define D_N 64
#define B_N 4
#define E_N 2000000

#define EDGES   (B_N * E_N)          // 8,000,000 per side
#define TOT     (2 * EDGES)          // 16,000,000 edge-entries
#define BU      (B_N * U_N)          // 400,000 user bins
#define BI      (B_N * I_N)          // 200,000 item bins
#define G_BINS  32                   // bins per chunk (LDS tile = 32x64 f32 = 8 KB)
#define G_SH    5
#define NSC_U   (BU / G_BINS)        // 12,500 user chunks (exact)
#define NSC_I   (BI / G_BINS)        // 6,250 item chunks (exact)
#define NSC     (NSC_U + NSC_I)      // 18,750 chunks, no phantom bins
#define CPAD    18752                // padded counter array length

// ---------------------------------------------------------------------------
// Entry mapping. Global entry gi in [0, TOT):
//   gi < EDGES : user side. bin = b*U + rows[gi], gathers item_emb[cols[gi]]
//   gi >= EDGES: item side. bin = b*I + cols[e],  gathers user_emb[rows[e]]
// ---------------------------------------------------------------------------
__device__ __forceinline__ void emap(int gi, const int* __restrict__ rows,
                                     const int* __restrict__ cols,
                                     int& chunk, int& local, int& s, int& e) {
    if (gi < EDGES) {
        int b = gi / E_N;
        int bin = b * U_N + rows[gi];
        chunk = bin >> G_SH; local = bin & (G_BINS - 1);
        s = cols[gi]; e = gi;
    } else {
        int e2 = gi - EDGES;
        int b = e2 / E_N;
        int bin = b * I_N + cols[e2];
        chunk = NSC_U + (bin >> G_SH); local = bin & (G_BINS - 1);
        s = rows[e2]; e = e2;
    }
}

// ---------------------------------------------------------------------------
// Pass 1: per-chunk histogram. LDS counters packed 2 x u16 per u32.
// (per-block per-chunk count <= entries/block ~ 62.5k? No: bounded by the
//  chunk's global total (~1-3k) << 65535, carry-safe.)
// ---------------------------------------------------------------------------
__global__ __launch_bounds__(256) void chist_kernel(const int* __restrict__ rows,
                                                    const int* __restrict__ cols,
                                                    int lo, int hi, int chunk_base,
                                                    int nsc, int* __restrict__ cnt) {
    __shared__ unsigned h[CPAD / 2];
    for (int i = threadIdx.x; i < CPAD / 2; i += 256) h[i] = 0;
    __syncthreads();
    int stride = gridDim.x * 256;
    for (int i = lo + blockIdx.x * 256 + threadIdx.x; i < hi; i += stride) {
        int chunk, local, s, e;
        emap(i, rows, cols, chunk, local, s, e);
        int rc = chunk - chunk_base;
        atomicAdd(&h[rc >> 1], 1u << ((rc & 1) * 16));
    }
    __syncthreads();
    int half = (nsc + 1) >> 1;
    for (int i = threadIdx.x; i < half; i += 256) {
        unsigned v = h[i];
        unsigned l16 = v & 0xFFFFu, h16 = v >> 16;
        if (l16) atomicAdd(&cnt[2 * i], (int)l16);
        if (h16) atomicAdd(&cnt[2 * i + 1], (int)h16);
    }
}

// ---------------------------------------------------------------------------
// Pass 2: exclusive scan over nsc (<= 18750) chunk counts, single block.
// ---------------------------------------------------------------------------
#define SC_T 19   // 1024*19 = 19456 >= 18750
__global__ __launch_bounds__(1024) void cscan_kernel(const int* __restrict__ cnt,
                                                     int* __restrict__ off,
                                                     int* __restrict__ cur, int nsc) {
    int t = threadIdx.x;
    int loc[SC_T];
    int s = 0;
#pragma unroll
    for (int j = 0; j < SC_T; ++j) {
        int idx = t * SC_T + j;
        int c = (idx < nsc) ? cnt[idx] : 0;
        loc[j] = s; s += c;
    }
    __shared__ int sm[1024];
    int mine = s;
    sm[t] = s; __syncthreads();
    for (int o = 1; o < 1024; o <<= 1) {
        int a = (t >= o) ? sm[t - o] : 0;
        __syncthreads();
        sm[t] += a;
        __syncthreads();
    }
    int pre = sm[t] - mine;
#pragma unroll
    for (int j = 0; j < SC_T; ++j) {
        int idx = t * SC_T + j;
        if (idx < nsc) { int o2 = pre + loc[j]; off[idx] = o2; cur[idx] = o2; }
    }
}

// ---------------------------------------------------------------------------
// Pass 3: partition. Payload carries everything accum needs:
//   payA = local_bin(5b)<<17 | src_idx(17b),  payB = v (f32).
// Scattered 8B stores land on 18750 active frontiers (~2.4 MB) -> L2-resident.
// ---------------------------------------------------------------------------
__global__ __launch_bounds__(256) void cpart_kernel(const int* __restrict__ rows,
                                                    const int* __restrict__ cols,
                                                    const float* __restrict__ vals,
                                                    int lo, int hi, int chunk_base,
                                                    int* __restrict__ cur,
                                                    unsigned* __restrict__ payA,
                                                    float* __restrict__ payB) {
    int i = lo + blockIdx.x * 256 + threadIdx.x;
    if (i >= hi) return;
    int chunk, local, s, e;
    emap(i, rows, cols, chunk, local, s, e);
    float v = vals[e];
    int pos = atomicAdd(&cur[chunk - chunk_base], 1);
    payA[pos] = ((unsigned)local << 17) | (unsigned)s;
    payB[pos] = v;
}

// ---------------------------------------------------------------------------
// Pass 4: per-chunk accumulate into a 32x64 f32 LDS tile.
// lane = dim (conflict-free ds_add); each of the 4 waves takes every 4th
// entry; pay loads are wave-uniform (HW broadcast). Unroll 2 for MLP.
// ---------------------------------------------------------------------------
__global__ __launch_bounds__(256) void accum_kernel(
        const float* __restrict__ user_emb,
        const float* __restrict__ item_emb,
        const int* __restrict__ off,
        const int* __restrict__ cnt,
        const unsigned* __restrict__ payA,
        const float* __restrict__ payB,
        float* __restrict__ stack_u,
        float* __restrict__ stack_i,
        int chunk_base) {
    int g = blockIdx.x;
    int abschunk = chunk_base + g;
    bool us = (abschunk < NSC_U);
    const float* emb = us ? item_emb : user_emb;
    int start = off[g];
    int n     = cnt[g];

    __shared__ float acc[G_BINS * 64];
    for (int i = threadIdx.x; i < G_BINS * 64; i += 256) acc[i] = 0.f;
    __syncthreads();

    int w = threadIdx.x >> 6, lane = threadIdx.x & 63;
#pragma unroll 2
    for (int j = w; j < n; j += 4) {
        unsigned p = payA[start + j];
        float    v = payB[start + j];
        int s     = (int)(p & 0x1FFFFu);
        int local = (int)(p >> 17);
        float x = emb[s * 64 + lane];
        atomicAdd(&acc[local * 64 + lane], v * x);
    }
    __syncthreads();

    const float4* a4 = (const float4*)acc;
    float4* d4 = us ? ((float4*)stack_u + (long long)abschunk * G_BINS * 16)
                    : ((float4*)stack_i + (long long)(abschunk - NSC_U) * G_BINS * 16);
    for (int i = threadIdx.x; i < G_BINS * 16; i += 256) d4[i] = a4[i];
}

// ---------------------------------------------------------------------------
// Fallback: atomic scatter (used only if ws too small for everything).
// ---------------------------------------------------------------------------
__global__ void scatter_atomic_kernel(const float* __restrict__ user_emb,
                                      const float* __restrict__ item_emb,
                                      const int* __restrict__ rows,
                                      const int* __restrict__ cols,
                                      const float* __restrict__ vals,
                                      float* __restrict__ stack_u,
                                      float* __restrict__ stack_i) {
    long long tid = (long long)blockIdx.x * blockDim.x + threadIdx.x;
    long long e  = tid >> 4;
    int lane = (int)(tid & 15);
    if (e >= (long long)EDGES) return;
    int b = (int)(e / E_N);
    int r = rows[e];
    int c = cols[e];
    float v = vals[e];
    const float4* irow = (const float4*)(item_emb + (long long)c * D_N);
    const float4* urow = (const float4*)(user_emb + (long long)r * D_N);
    float4 iv = irow[lane];
    float4 uv = urow[lane];
    float* du = stack_u + ((long long)b * U_N + r) * D_N + lane * 4;
    float* di = stack_i + ((long long)b * I_N + c) * D_N + lane * 4;
    atomicAdd(du + 0, v * iv.x);
    atomicAdd(du + 1, v * iv.y);
    atomicAdd(du + 2, v * iv.z);
    atomicAdd(du + 3, v * iv.w);
    atomicAdd(di + 0, v * uv.x);
    atomicAdd(di + 1, v * uv.y);
    atomicAdd(di + 2, v * uv.z);
    atomicAdd(di + 3, v * uv.w);
}

// ---------------------------------------------------------------------------
// Phase 2: per-row dense transform + sigmoid, in place (unchanged).
// ---------------------------------------------------------------------------
template <int NROWS>
__global__ __launch_bounds__(64) void transform_kernel(
        float* __restrict__ stack,       // [B, NROWS, D] in/out
        const float* __restrict__ W,     // [D, D]
        float* __restrict__ mean_out) {  // [NROWS, D]
    const int row = blockIdx.x;
    const int j   = threadIdx.x;

    __shared__ float xs[B_N][D_N];
#pragma unroll
    for (int b = 0; b < B_N; ++b)
        xs[b][j] = stack[((long long)b * NROWS + row) * D_N + j];
    __syncthreads();

    float acc[B_N] = {0.f, 0.f, 0.f, 0.f};
#pragma unroll 8
    for (int d = 0; d < D_N; ++d) {
        float w = W[d * D_N + j];
#pragma unroll
        for (int b = 0; b < B_N; ++b)
            acc[b] += xs[b][d] * w;
    }

    float m = 0.25f * (acc[0] + acc[1] + acc[2] + acc[3]);
#pragma unroll
    for (int b = 0; b < B_N; ++b)
        stack[((long long)b * NROWS + row) * D_N + j] =
            1.0f / (1.0f + __expf(-acc[b]));
    mean_out[(long long)row * D_N + j] = 1.0f / (1.0f + __expf(-m));
}

// ---------------------------------------------------------------------------
extern "C" void kernel_launch(void* const* d_in, const int* in_sizes, int n_in,
                              void* d_out, int out_size, void* d_ws, size_t ws_size,
                              hipStream_t stream) {
    const float* user_emb = (const float*)d_in[0];
    const float* item_emb = (const float*)d_in[1];
    const int*   rows     = (const int*)  d_in[2];
    const int*   cols     = (const int*)  d_in[3];
    const float* vals     = (const float*)d_in[4];
    const float* u_w      = (const float*)d_in[5];
    const float* i_w      = (const float*)d_in[6];

    float* out = (float*)d_out;
    float* user_mean = out;
    float* item_mean = out + (long long)U_N * D_N;
    float* stack_u   = item_mean + (long long)I_N * D_N;     // [B,U,D] out
    float* stack_i   = stack_u + (long long)B_N * U_N * D_N; // [B,I,D] out

    size_t hdr   = (size_t)3 * CPAD * sizeof(int);           // cnt/off/cur
    size_t need1 = hdr + (size_t)TOT   * 8;                  // ~128.3 MB
    size_t need2 = hdr + (size_t)EDGES * 8;                  // ~64.3 MB

    int* cnt = (int*)d_ws;
    int* off = cnt + CPAD;
    int* cur = off + CPAD;
    unsigned* payA;
    float*    payB;

    if (ws_size >= need1) {
        // Single shot: both sides in one pipeline (18750 chunks).
        payA = (unsigned*)(cur + CPAD);
        payB = (float*)(payA + TOT);
        hipMemsetAsync(cnt, 0, (size_t)NSC * sizeof(int), stream);
        chist_kernel<<<256, 256, 0, stream>>>(rows, cols, 0, TOT, 0, NSC, cnt);
        cscan_kernel<<<1, 1024, 0, stream>>>(cnt, off, cur, NSC);
        cpart_kernel<<<TOT / 256, 256, 0, stream>>>(rows, cols, vals, 0, TOT, 0,
                                                    cur, payA, payB);
        accum_kernel<<<NSC, 256, 0, stream>>>(user_emb, item_emb, off, cnt,
                                              payA, payB, stack_u, stack_i, 0);
    } else if (ws_size >= need2) {
        // Two rounds: user side then item side, sharing the payload buffer.
        payA = (unsigned*)(cur + CPAD);
        payB = (float*)(payA + EDGES);
        // Round A: user side, chunks [0, NSC_U)
        hipMemsetAsync(cnt, 0, (size_t)NSC_U * sizeof(int), stream);
        chist_kernel<<<256, 256, 0, stream>>>(rows, cols, 0, EDGES, 0, NSC_U, cnt);
        cscan_kernel<<<1, 1024, 0, stream>>>(cnt, off, cur, NSC_U);
        cpart_kernel<<<EDGES / 256, 256, 0, stream>>>(rows, cols, vals, 0, EDGES,
                                                      0, cur, payA, payB);
        accum_kernel<<<NSC_U, 256, 0, stream>>>(user_emb, item_emb, off, cnt,
                                                payA, payB, stack_u, stack_i, 0);
        // Round B: item side, chunks [NSC_U, NSC)
        hipMemsetAsync(cnt, 0, (size_t)NSC_I * sizeof(int), stream);
        chist_kernel<<<256, 256, 0, stream>>>(rows, cols, EDGES, TOT, NSC_U,
                                              NSC_I, cnt);
        cscan_kernel<<<1, 1024, 0, stream>>>(cnt, off, cur, NSC_I);
        cpart_kernel<<<EDGES / 256, 256, 0, stream>>>(rows, cols, vals, EDGES,
                                                      TOT, NSC_U, cur, payA, payB);
        accum_kernel<<<NSC_I, 256, 0, stream>>>(user_emb, item_emb, off, cnt,
                                                payA, payB, stack_u, stack_i,
                                                NSC_U);
    } else {
        size_t stack_bytes = sizeof(float) * (size_t)B_N * (U_N + I_N) * D_N;
        hipMemsetAsync(stack_u, 0, stack_bytes, stream);
        long long nthreads = (long long)EDGES * 16;
        int nblocks = (int)((nthreads + 255) / 256);
        scatter_atomic_kernel<<<nblocks, 256, 0, stream>>>(
            user_emb, item_emb, rows, cols, vals, stack_u, stack_i);
    }

    transform_kernel<U_N><<<U_N, 64, 0, stream>>>(stack_u, u_w, user_mean);
    transform_kernel<I_N><<<I_N, 64, 0, stream>>>(stack_i, i_w, item_mean);
}

// Round 5
// 2583.836 us; speedup vs baseline: 3.1511x; 2.6735x over previous
//
#include <hip/hip_runtime.h>

#define U_N 100000
#define I_N 50000
#define D_N 64
#define B_N 4
#define E_N 2000000

#define EDGES   (B_N * E_N)          // 8,000,000 per side
#define TOT     (2 * EDGES)          // 16,000,000 edge-entries
#define BU      (B_N * U_N)          // 400,000 user bins
#define BI      (B_N * I_N)          // 200,000 item bins
#define G_BINS  32
#define G_SH    5
#define NSC_U   (BU / G_BINS)        // 12,500 user chunks (exact)
#define NSC_I   (BI / G_BINS)        // 6,250 item chunks (exact)
#define CPAD_S  12512                // padded per-side counter length (even)
#define CAP     4096                 // binsort LDS staging capacity (entries)

// ---------------------------------------------------------------------------
// Entry mapping. Global entry gi in [0, TOT):
//   gi < EDGES : user side. bin = b*U + rows[gi], gathers item table [cols[gi]]
//   gi >= EDGES: item side. bin = b*I + cols[e],  gathers user table [rows[e]]
// ---------------------------------------------------------------------------
__device__ __forceinline__ void emap(int gi, const int* __restrict__ rows,
                                     const int* __restrict__ cols,
                                     int& chunk, int& local, int& s, int& e) {
    if (gi < EDGES) {
        int b = gi / E_N;
        int bin = b * U_N + rows[gi];
        chunk = bin >> G_SH; local = bin & (G_BINS - 1);
        s = cols[gi]; e = gi;
    } else {
        int e2 = gi - EDGES;
        int b = e2 / E_N;
        int bin = b * I_N + cols[e2];
        chunk = NSC_U + (bin >> G_SH); local = bin & (G_BINS - 1);
        s = rows[e2]; e = e2;
    }
}

// ---------------------------------------------------------------------------
// Pass 0: convert both embedding tables to bf16 (RNE). Halves gather bytes.
// ---------------------------------------------------------------------------
__global__ __launch_bounds__(256) void cvt_kernel(const float* __restrict__ ue,
                                                  const float* __restrict__ ie,
                                                  unsigned short* __restrict__ u16,
                                                  unsigned short* __restrict__ i16) {
    int i = blockIdx.x * 256 + threadIdx.x;
    int nu = U_N * D_N;
    int ni = I_N * D_N;
    if (i < nu) {
        unsigned u = __float_as_uint(ue[i]);
        u += 0x7FFFu + ((u >> 16) & 1u);
        u16[i] = (unsigned short)(u >> 16);
    } else if (i < nu + ni) {
        int j = i - nu;
        unsigned u = __float_as_uint(ie[j]);
        u += 0x7FFFu + ((u >> 16) & 1u);
        i16[j] = (unsigned short)(u >> 16);
    }
}

// ---------------------------------------------------------------------------
// Pass 1: per-chunk histogram (per side). LDS counters packed 2 x u16.
// ---------------------------------------------------------------------------
__global__ __launch_bounds__(256) void chist_kernel(const int* __restrict__ rows,
                                                    const int* __restrict__ cols,
                                                    int lo, int hi, int chunk_base,
                                                    int* __restrict__ cnt) {
    __shared__ unsigned h[CPAD_S / 2];
    for (int i = threadIdx.x; i < CPAD_S / 2; i += 256) h[i] = 0;
    __syncthreads();
    int stride = gridDim.x * 256;
    for (int i = lo + blockIdx.x * 256 + threadIdx.x; i < hi; i += stride) {
        int chunk, local, s, e;
        emap(i, rows, cols, chunk, local, s, e);
        int rc = chunk - chunk_base;
        atomicAdd(&h[rc >> 1], 1u << ((rc & 1) * 16));
    }
    __syncthreads();
    for (int i = threadIdx.x; i < CPAD_S / 2; i += 256) {
        unsigned v = h[i];
        unsigned l16 = v & 0xFFFFu, h16 = v >> 16;
        if (l16) atomicAdd(&cnt[2 * i], (int)l16);
        if (h16) atomicAdd(&cnt[2 * i + 1], (int)h16);
    }
}

// ---------------------------------------------------------------------------
// Pass 2: exclusive scan over nsc (<= 12500) chunk counts, single block.
// ---------------------------------------------------------------------------
#define SC_T 13   // 1024*13 = 13312 >= 12512
__global__ __launch_bounds__(1024) void cscan_kernel(const int* __restrict__ cnt,
                                                     int* __restrict__ off,
                                                     int* __restrict__ cur, int nsc) {
    int t = threadIdx.x;
    int loc[SC_T];
    int s = 0;
#pragma unroll
    for (int j = 0; j < SC_T; ++j) {
        int idx = t * SC_T + j;
        int c = (idx < nsc) ? cnt[idx] : 0;
        loc[j] = s; s += c;
    }
    __shared__ int sm[1024];
    int mine = s;
    sm[t] = s; __syncthreads();
    for (int o = 1; o < 1024; o <<= 1) {
        int a = (t >= o) ? sm[t - o] : 0;
        __syncthreads();
        sm[t] += a;
        __syncthreads();
    }
    int pre = sm[t] - mine;
#pragma unroll
    for (int j = 0; j < SC_T; ++j) {
        int idx = t * SC_T + j;
        if (idx < nsc) { int o2 = pre + loc[j]; off[idx] = o2; cur[idx] = o2; }
    }
}

// ---------------------------------------------------------------------------
// Pass 3: partition into chunk segments. pay = { local<<17 | src, f32 val }.
// ~12.5k active frontiers -> L2-resident, ~1x write amplification.
// ---------------------------------------------------------------------------
__global__ __launch_bounds__(256) void cpart_kernel(const int* __restrict__ rows,
                                                    const int* __restrict__ cols,
                                                    const float* __restrict__ vals,
                                                    int lo, int hi, int chunk_base,
                                                    int* __restrict__ cur,
                                                    uint2* __restrict__ pay) {
    int i = lo + blockIdx.x * 256 + threadIdx.x;
    if (i >= hi) return;
    int chunk, local, s, e;
    emap(i, rows, cols, chunk, local, s, e);
    float v = vals[e];
    int pos = atomicAdd(&cur[chunk - chunk_base], 1);
    pay[pos] = make_uint2(((unsigned)local << 17) | (unsigned)s,
                          __float_as_uint(v));
}

// ---------------------------------------------------------------------------
// Pass 4: per-chunk counting sort by 5-bit local bin (in place, LDS bounce).
// Writes absolute per-bin start offsets to binoff[g*32+b]; flags[g]=1 if
// sorted (n <= CAP; for this input max chunk ~1.5k << 4096).
// ---------------------------------------------------------------------------
__global__ __launch_bounds__(256) void binsort_kernel(const int* __restrict__ off,
                                                      const int* __restrict__ cnt,
                                                      uint2* __restrict__ pay,
                                                      int* __restrict__ binoff,
                                                      int* __restrict__ flags) {
    int g = blockIdx.x;
    int start = off[g], n = cnt[g];
    __shared__ uint2 st[CAP];
    __shared__ uint2 st2[CAP];
    __shared__ int c32[G_BINS], cs[G_BINS];
    if (n > CAP) {                       // never for this input; accum fallback
        if (threadIdx.x == 0) flags[g] = 0;
        if (threadIdx.x < G_BINS) binoff[g * G_BINS + threadIdx.x] = start;
        return;
    }
    if (threadIdx.x == 0) flags[g] = 1;
    if (threadIdx.x < G_BINS) c32[threadIdx.x] = 0;
    __syncthreads();
    for (int i = threadIdx.x; i < n; i += 256) {
        uint2 p = pay[start + i];
        st[i] = p;
        atomicAdd(&c32[p.x >> 17], 1);
    }
    __syncthreads();
    if (threadIdx.x == 0) {
        int s = 0;
        for (int b = 0; b < G_BINS; ++b) {
            cs[b] = s;
            binoff[g * G_BINS + b] = start + s;
            s += c32[b];
        }
    }
    __syncthreads();
    for (int i = threadIdx.x; i < n; i += 256) {
        uint2 p = st[i];
        int pos = atomicAdd(&cs[p.x >> 17], 1);
        st2[pos] = p;
    }
    __syncthreads();
    for (int i = threadIdx.x; i < n; i += 256)
        pay[start + i] = st2[i];
}

// ---------------------------------------------------------------------------
// Pass 5: accumulate. Sorted path: wave owns 8 contiguous bins; REGISTER
// accumulation (no LDS ops at all); one plain 256B store per bin. Gathers
// are bf16 rows (128B, coalesced). Fallback path (unsorted): ds_add tile.
// ---------------------------------------------------------------------------
__global__ __launch_bounds__(256) void accum_kernel(
        const unsigned short* __restrict__ emb16,  // gather table (bf16)
        const int* __restrict__ off,
        const int* __restrict__ cnt,
        const int* __restrict__ binoff,
        const int* __restrict__ flags,
        const uint2* __restrict__ pay,
        float* __restrict__ dst) {                 // side stack base
    int g = blockIdx.x;
    int w = threadIdx.x >> 6, lane = threadIdx.x & 63;
    int start = off[g], n = cnt[g];
    long long base = (long long)g * (G_BINS * 64);

    __shared__ float tile[G_BINS * 64];            // used by fallback only

    if (flags[g]) {
#pragma unroll
        for (int bi = 0; bi < 8; ++bi) {
            int b = w * 8 + bi;
            int s0 = binoff[g * G_BINS + b];
            int s1 = (b == G_BINS - 1) ? (start + n) : binoff[g * G_BINS + b + 1];
            float acc = 0.f;
#pragma unroll 4
            for (int j = s0; j < s1; ++j) {
                uint2 pv = pay[j];
                int src = (int)(pv.x & 0x1FFFFu);
                float x = __uint_as_float((unsigned)emb16[src * 64 + lane] << 16);
                acc = fmaf(__uint_as_float(pv.y), x, acc);
            }
            dst[base + (long long)b * 64 + lane] = acc;
        }
    } else {
        for (int i = threadIdx.x; i < G_BINS * 64; i += 256) tile[i] = 0.f;
        __syncthreads();
        for (int j = w; j < n; j += 4) {
            uint2 pv = pay[start + j];
            int src   = (int)(pv.x & 0x1FFFFu);
            int local = (int)(pv.x >> 17);
            float x = __uint_as_float((unsigned)emb16[src * 64 + lane] << 16);
            atomicAdd(&tile[local * 64 + lane], __uint_as_float(pv.y) * x);
        }
        __syncthreads();
        for (int i = threadIdx.x; i < G_BINS * 64; i += 256) dst[base + i] = tile[i];
    }
}

// ---------------------------------------------------------------------------
// Deep fallback: atomic scatter (only if ws is impossibly small).
// ---------------------------------------------------------------------------
__global__ void scatter_atomic_kernel(const float* __restrict__ user_emb,
                                      const float* __restrict__ item_emb,
                                      const int* __restrict__ rows,
                                      const int* __restrict__ cols,
                                      const float* __restrict__ vals,
                                      float* __restrict__ stack_u,
                                      float* __restrict__ stack_i) {
    long long tid = (long long)blockIdx.x * blockDim.x + threadIdx.x;
    long long e  = tid >> 4;
    int lane = (int)(tid & 15);
    if (e >= (long long)EDGES) return;
    int b = (int)(e / E_N);
    int r = rows[e];
    int c = cols[e];
    float v = vals[e];
    const float4* irow = (const float4*)(item_emb + (long long)c * D_N);
    const float4* urow = (const float4*)(user_emb + (long long)r * D_N);
    float4 iv = irow[lane];
    float4 uv = urow[lane];
    float* du = stack_u + ((long long)b * U_N + r) * D_N + lane * 4;
    float* di = stack_i + ((long long)b * I_N + c) * D_N + lane * 4;
    atomicAdd(du + 0, v * iv.x);
    atomicAdd(du + 1, v * iv.y);
    atomicAdd(du + 2, v * iv.z);
    atomicAdd(du + 3, v * iv.w);
    atomicAdd(di + 0, v * uv.x);
    atomicAdd(di + 1, v * uv.y);
    atomicAdd(di + 2, v * uv.z);
    atomicAdd(di + 3, v * uv.w);
}

// ---------------------------------------------------------------------------
// Phase 2: per-row dense transform + sigmoid, in place (unchanged).
// ---------------------------------------------------------------------------
template <int NROWS>
__global__ __launch_bounds__(64) void transform_kernel(
        float* __restrict__ stack,       // [B, NROWS, D] in/out
        const float* __restrict__ W,     // [D, D]
        float* __restrict__ mean_out) {  // [NROWS, D]
    const int row = blockIdx.x;
    const int j   = threadIdx.x;

    __shared__ float xs[B_N][D_N];
#pragma unroll
    for (int b = 0; b < B_N; ++b)
        xs[b][j] = stack[((long long)b * NROWS + row) * D_N + j];
    __syncthreads();

    float acc[B_N] = {0.f, 0.f, 0.f, 0.f};
#pragma unroll 8
    for (int d = 0; d < D_N; ++d) {
        float w = W[d * D_N + j];
#pragma unroll
        for (int b = 0; b < B_N; ++b)
            acc[b] += xs[b][d] * w;
    }

    float m = 0.25f * (acc[0] + acc[1] + acc[2] + acc[3]);
#pragma unroll
    for (int b = 0; b < B_N; ++b)
        stack[((long long)b * NROWS + row) * D_N + j] =
            1.0f / (1.0f + __expf(-acc[b]));
    mean_out[(long long)row * D_N + j] = 1.0f / (1.0f + __expf(-m));
}

// ---------------------------------------------------------------------------
extern "C" void kernel_launch(void* const* d_in, const int* in_sizes, int n_in,
                              void* d_out, int out_size, void* d_ws, size_t ws_size,
                              hipStream_t stream) {
    const float* user_emb = (const float*)d_in[0];
    const float* item_emb = (const float*)d_in[1];
    const int*   rows     = (const int*)  d_in[2];
    const int*   cols     = (const int*)  d_in[3];
    const float* vals     = (const float*)d_in[4];
    const float* u_w      = (const float*)d_in[5];
    const float* i_w      = (const float*)d_in[6];

    float* out = (float*)d_out;
    float* user_mean = out;
    float* item_mean = out + (long long)U_N * D_N;
    float* stack_u   = item_mean + (long long)I_N * D_N;     // [B,U,D] out
    float* stack_i   = stack_u + (long long)B_N * U_N * D_N; // [B,I,D] out

    // Workspace layout (sized for the larger, user, side; reused per round):
    //   cnt/off/cur: CPAD_S each | binoff: NSC_U*32 | flags: CPAD_S
    //   pay: EDGES uint2 (64 MB) | user16: U*64 u16 | item16: I*64 u16
    int* cnt    = (int*)d_ws;
    int* off    = cnt + CPAD_S;
    int* cur    = off + CPAD_S;
    int* binoff = cur + CPAD_S;
    int* flags  = binoff + NSC_U * G_BINS;
    uint2* pay  = (uint2*)(flags + CPAD_S);
    unsigned short* user16 = (unsigned short*)(pay + EDGES);
    unsigned short* item16 = user16 + (size_t)U_N * D_N;
    size_t needed = (size_t)((4 * CPAD_S + NSC_U * G_BINS) * 4) +
                    (size_t)EDGES * 8 + (size_t)(U_N + I_N) * D_N * 2;

    if (ws_size >= needed) {
        // bf16 tables
        int ncvt = (U_N + I_N) * D_N;
        cvt_kernel<<<(ncvt + 255) / 256, 256, 0, stream>>>(user_emb, item_emb,
                                                           user16, item16);
        // ---- Round A: user side (gathers item table, 6.4 MB bf16) ----
        hipMemsetAsync(cnt, 0, (size_t)CPAD_S * sizeof(int), stream);
        chist_kernel<<<256, 256, 0, stream>>>(rows, cols, 0, EDGES, 0, cnt);
        cscan_kernel<<<1, 1024, 0, stream>>>(cnt, off, cur, NSC_U);
        cpart_kernel<<<EDGES / 256, 256, 0, stream>>>(rows, cols, vals, 0, EDGES,
                                                      0, cur, pay);
        binsort_kernel<<<NSC_U, 256, 0, stream>>>(off, cnt, pay, binoff, flags);
        accum_kernel<<<NSC_U, 256, 0, stream>>>(item16, off, cnt, binoff, flags,
                                                pay, stack_u);
        // ---- Round B: item side (gathers user table, 12.8 MB bf16) ----
        hipMemsetAsync(cnt, 0, (size_t)CPAD_S * sizeof(int), stream);
        chist_kernel<<<256, 256, 0, stream>>>(rows, cols, EDGES, TOT, NSC_U, cnt);
        cscan_kernel<<<1, 1024, 0, stream>>>(cnt, off, cur, NSC_I);
        cpart_kernel<<<EDGES / 256, 256, 0, stream>>>(rows, cols, vals, EDGES,
                                                      TOT, NSC_U, cur, pay);
        binsort_kernel<<<NSC_I, 256, 0, stream>>>(off, cnt, pay, binoff, flags);
        accum_kernel<<<NSC_I, 256, 0, stream>>>(user16, off, cnt, binoff, flags,
                                                pay, stack_i);
    } else {
        size_t stack_bytes = sizeof(float) * (size_t)B_N * (U_N + I_N) * D_N;
        hipMemsetAsync(stack_u, 0, stack_bytes, stream);
        long long nthreads = (long long)EDGES * 16;
        int nblocks = (int)((nthreads + 255) / 256);
        scatter_atomic_kernel<<<nblocks, 256, 0, stream>>>(
            user_emb, item_emb, rows, cols, vals, stack_u, stack_i);
    }

    transform_kernel<U_N><<<U_N, 64, 0, stream>>>(stack_u, u_w, user_mean);
    transform_kernel<I_N><<<I_N, 64, 0, stream>>>(stack_i, i_w, item_mean);
}

// Round 6
// 1823.637 us; speedup vs baseline: 4.4647x; 1.4169x over previous
//
#include <hip/hip_runtime.h>

#define U_N 100000
#define I_N 50000
#define D_N 64
#define B_N 4
#define E_N 2000000

#define EDGES   (B_N * E_N)          // 8,000,000 entries per side
#define TOT     (2 * EDGES)
#define BU      (B_N * U_N)          // 400,000 user bins
#define BI      (B_N * I_N)          // 200,000 item bins
#define G_BINS  32
#define G_SH    5
#define NSC_U   (BU / G_BINS)        // 12,500 user chunks
#define NSC_I   (BI / G_BINS)        // 6,250 item chunks
#define CPAD_S  12512                // padded per-side chunk count (even)
#define CAP     4096                 // binsort LDS capacity (entries)
#define NSL     8                    // slices == XCDs
#define SLICE   (EDGES / NSL)        // 1,000,000 entries per slice
#define CPB     512                  // cpart blocks per slice
#define SCB_U   ((NSC_U + 255) / 256)  // 49 scan blocks (user)
#define SCB_I   ((NSC_I + 255) / 256)  // 25 scan blocks (item)

// ---------------------------------------------------------------------------
// Entry mapping. Global entry gi in [0, TOT):
//   gi < EDGES : user side. bin = b*U + rows[gi]; gathers item table [cols[gi]]
//   gi >= EDGES: item side. bin = b*I + cols[e];  gathers user table [rows[e]]
// ---------------------------------------------------------------------------
__device__ __forceinline__ void emap(int gi, const int* __restrict__ rows,
                                     const int* __restrict__ cols,
                                     int& chunk, int& local, int& s, int& e) {
    if (gi < EDGES) {
        int b = gi / E_N;
        int bin = b * U_N + rows[gi];
        chunk = bin >> G_SH; local = bin & (G_BINS - 1);
        s = cols[gi]; e = gi;
    } else {
        int e2 = gi - EDGES;
        int b = e2 / E_N;
        int bin = b * I_N + cols[e2];
        chunk = NSC_U + (bin >> G_SH); local = bin & (G_BINS - 1);
        s = rows[e2]; e = e2;
    }
}

__device__ __forceinline__ int chunk_of(int gi, const int* __restrict__ rows,
                                        const int* __restrict__ cols) {
    if (gi < EDGES) {
        int b = gi / E_N;
        return (b * U_N + rows[gi]) >> G_SH;
    }
    int e = gi - EDGES;
    int b = e / E_N;
    return NSC_U + ((b * I_N + cols[e]) >> G_SH);
}

// ---------------------------------------------------------------------------
// Pass 0: convert both embedding tables to bf16 (RNE).
// ---------------------------------------------------------------------------
__global__ __launch_bounds__(256) void cvt_kernel(const float* __restrict__ ue,
                                                  const float* __restrict__ ie,
                                                  unsigned short* __restrict__ u16,
                                                  unsigned short* __restrict__ i16) {
    int i = blockIdx.x * 256 + threadIdx.x;
    int nu = U_N * D_N;
    int ni = I_N * D_N;
    if (i < nu) {
        unsigned u = __float_as_uint(ue[i]);
        u += 0x7FFFu + ((u >> 16) & 1u);
        u16[i] = (unsigned short)(u >> 16);
    } else if (i < nu + ni) {
        int j = i - nu;
        unsigned u = __float_as_uint(ie[j]);
        u += 0x7FFFu + ((u >> 16) & 1u);
        i16[j] = (unsigned short)(u >> 16);
    }
}

// ---------------------------------------------------------------------------
// Pass 1: per-(chunk, slice) histogram. Block b handles slice b&7 only;
// 32 blocks per slice grid-stride its contiguous 1M entries. LDS u16x2.
// ---------------------------------------------------------------------------
__global__ __launch_bounds__(256) void chist_kernel(const int* __restrict__ rows,
                                                    const int* __restrict__ cols,
                                                    int lo, int chunk_base,
                                                    int* __restrict__ cnt_sm) {
    int sl = blockIdx.x & (NSL - 1);
    int kb = blockIdx.x >> 3;                 // 0..31
    int base = lo + sl * SLICE;
    __shared__ unsigned h[CPAD_S / 2];
    for (int i = threadIdx.x; i < CPAD_S / 2; i += 256) h[i] = 0;
    __syncthreads();
    for (int i = kb * 256 + threadIdx.x; i < SLICE; i += 32 * 256) {
        int rc = chunk_of(base + i, rows, cols) - chunk_base;
        atomicAdd(&h[rc >> 1], 1u << ((rc & 1) * 16));
    }
    __syncthreads();
    int* cnt = cnt_sm + sl * CPAD_S;          // slice-private counter block
    for (int i = threadIdx.x; i < CPAD_S / 2; i += 256) {
        unsigned v = h[i];
        if (v & 0xFFFFu) atomicAdd(&cnt[2 * i], (int)(v & 0xFFFFu));
        if (v >> 16)     atomicAdd(&cnt[2 * i + 1], (int)(v >> 16));
    }
}

// ---------------------------------------------------------------------------
// Pass 2: scan in CHUNK-MAJOR logical order (m = chunk*8 + slice) over
// slice-major storage -> chunk segments contiguous in pay, slice
// sub-segments adjacent. One chunk per thread (8 items).
// ---------------------------------------------------------------------------
__global__ __launch_bounds__(256) void scan_a(const int* __restrict__ cnt_sm,
                                              int nsc, int* __restrict__ bsum) {
    int t = threadIdx.x;
    int c = blockIdx.x * 256 + t;
    int s = 0;
    if (c < nsc) {
#pragma unroll
        for (int j = 0; j < NSL; ++j) s += cnt_sm[j * CPAD_S + c];
    }
    __shared__ int sm[256];
    sm[t] = s; __syncthreads();
    for (int o = 128; o > 0; o >>= 1) {
        if (t < o) sm[t] += sm[t + o];
        __syncthreads();
    }
    if (t == 0) bsum[blockIdx.x] = sm[0];
}

__global__ __launch_bounds__(256) void scan_b(int* __restrict__ bsum, int nblk) {
    int t = threadIdx.x;
    __shared__ int sm[256];
    int v = (t < nblk) ? bsum[t] : 0;
    sm[t] = v; __syncthreads();
    for (int o = 1; o < 256; o <<= 1) {
        int a = (t >= o) ? sm[t - o] : 0;
        __syncthreads();
        sm[t] += a;
        __syncthreads();
    }
    if (t < nblk) bsum[t] = sm[t] - v;        // exclusive
}

__global__ __launch_bounds__(256) void scan_c(const int* __restrict__ cnt_sm,
                                              const int* __restrict__ bsum, int nsc,
                                              int* __restrict__ off_sm,
                                              int* __restrict__ cur_sm,
                                              int* __restrict__ off_ch,
                                              int* __restrict__ cnt_ch) {
    int t = threadIdx.x;
    int c = blockIdx.x * 256 + t;
    int loc[NSL]; int s = 0;
#pragma unroll
    for (int j = 0; j < NSL; ++j) {
        int v = (c < nsc) ? cnt_sm[j * CPAD_S + c] : 0;
        loc[j] = s; s += v;
    }
    __shared__ int sm[256];
    int mine = s;
    sm[t] = s; __syncthreads();
    for (int o = 1; o < 256; o <<= 1) {
        int a = (t >= o) ? sm[t - o] : 0;
        __syncthreads();
        sm[t] += a;
        __syncthreads();
    }
    int pre = bsum[blockIdx.x] + sm[t] - mine;
    if (c < nsc) {
        off_ch[c] = pre; cnt_ch[c] = mine;
#pragma unroll
        for (int j = 0; j < NSL; ++j) {
            int o2 = pre + loc[j];
            off_sm[j * CPAD_S + c] = o2;
            cur_sm[j * CPAD_S + c] = o2;
        }
    }
}

// ---------------------------------------------------------------------------
// Pass 3: XCD-affine partition. Block b -> slice b&7 (one XCD by round-robin
// heuristic); writes only its slice's cursors + pay sub-segments, so every
// frontier cacheline has a single-XCD writer set -> L2-absorbed full lines.
// ---------------------------------------------------------------------------
__global__ __launch_bounds__(256) void cpart_kernel(const int* __restrict__ rows,
                                                    const int* __restrict__ cols,
                                                    const float* __restrict__ vals,
                                                    int lo, int chunk_base,
                                                    int* __restrict__ cur_sm,
                                                    uint2* __restrict__ pay) {
    int sl = blockIdx.x & (NSL - 1);
    int kb = blockIdx.x >> 3;                 // 0..CPB-1
    int base = lo + sl * SLICE;
    int* cur = cur_sm + sl * CPAD_S;
    for (int i = kb * 256 + threadIdx.x; i < SLICE; i += CPB * 256) {
        int gi = base + i;
        int chunk, local, src, e;
        emap(gi, rows, cols, chunk, local, src, e);
        float v = vals[e];
        int pos = atomicAdd(&cur[chunk - chunk_base], 1);
        pay[pos] = make_uint2(((unsigned)local << 17) | (unsigned)src,
                              __float_as_uint(v));
    }
}

// ---------------------------------------------------------------------------
// Pass 4: per-chunk counting sort by 5-bit local bin (LDS bounce, in place).
// ---------------------------------------------------------------------------
__global__ __launch_bounds__(256) void binsort_kernel(const int* __restrict__ off_ch,
                                                      const int* __restrict__ cnt_ch,
                                                      uint2* __restrict__ pay,
                                                      int* __restrict__ binoff,
                                                      int* __restrict__ flags) {
    int g = blockIdx.x;
    int start = off_ch[g], n = cnt_ch[g];
    __shared__ uint2 st[CAP];
    __shared__ uint2 st2[CAP];
    __shared__ int c32[G_BINS], cs[G_BINS];
    if (n > CAP) {                            // never for this input
        if (threadIdx.x == 0) flags[g] = 0;
        if (threadIdx.x < G_BINS) binoff[g * G_BINS + threadIdx.x] = start;
        return;
    }
    if (threadIdx.x == 0) flags[g] = 1;
    if (threadIdx.x < G_BINS) c32[threadIdx.x] = 0;
    __syncthreads();
    for (int i = threadIdx.x; i < n; i += 256) {
        uint2 p = pay[start + i];
        st[i] = p;
        atomicAdd(&c32[p.x >> 17], 1);
    }
    __syncthreads();
    if (threadIdx.x == 0) {
        int s = 0;
        for (int b = 0; b < G_BINS; ++b) {
            cs[b] = s;
            binoff[g * G_BINS + b] = start + s;
            s += c32[b];
        }
    }
    __syncthreads();
    for (int i = threadIdx.x; i < n; i += 256) {
        uint2 p = st[i];
        int pos = atomicAdd(&cs[p.x >> 17], 1);
        st2[pos] = p;
    }
    __syncthreads();
    for (int i = threadIdx.x; i < n; i += 256)
        pay[start + i] = st2[i];
}

// ---------------------------------------------------------------------------
// Pass 5: accumulate. Wave owns 8 contiguous bins; register accumulation;
// one plain 256B store per bin; bf16 gathers (128B rows).
// ---------------------------------------------------------------------------
__global__ __launch_bounds__(256) void accum_kernel(
        const unsigned short* __restrict__ emb16,
        const int* __restrict__ off_ch,
        const int* __restrict__ cnt_ch,
        const int* __restrict__ binoff,
        const int* __restrict__ flags,
        const uint2* __restrict__ pay,
        float* __restrict__ dst) {
    int g = blockIdx.x;
    int w = threadIdx.x >> 6, lane = threadIdx.x & 63;
    int start = off_ch[g], n = cnt_ch[g];
    long long base = (long long)g * (G_BINS * 64);

    __shared__ float tile[G_BINS * 64];       // fallback path only

    if (flags[g]) {
#pragma unroll
        for (int bi = 0; bi < 8; ++bi) {
            int b = w * 8 + bi;
            int s0 = binoff[g * G_BINS + b];
            int s1 = (b == G_BINS - 1) ? (start + n) : binoff[g * G_BINS + b + 1];
            float acc = 0.f;
#pragma unroll 4
            for (int j = s0; j < s1; ++j) {
                uint2 pv = pay[j];
                int src = (int)(pv.x & 0x1FFFFu);
                float x = __uint_as_float((unsigned)emb16[src * 64 + lane] << 16);
                acc = fmaf(__uint_as_float(pv.y), x, acc);
            }
            dst[base + (long long)b * 64 + lane] = acc;
        }
    } else {
        for (int i = threadIdx.x; i < G_BINS * 64; i += 256) tile[i] = 0.f;
        __syncthreads();
        for (int j = w; j < n; j += 4) {
            uint2 pv = pay[start + j];
            int src   = (int)(pv.x & 0x1FFFFu);
            int local = (int)(pv.x >> 17);
            float x = __uint_as_float((unsigned)emb16[src * 64 + lane] << 16);
            atomicAdd(&tile[local * 64 + lane], __uint_as_float(pv.y) * x);
        }
        __syncthreads();
        for (int i = threadIdx.x; i < G_BINS * 64; i += 256) dst[base + i] = tile[i];
    }
}

// ---------------------------------------------------------------------------
// Deep fallback: atomic scatter (only if ws is impossibly small).
// ---------------------------------------------------------------------------
__global__ void scatter_atomic_kernel(const float* __restrict__ user_emb,
                                      const float* __restrict__ item_emb,
                                      const int* __restrict__ rows,
                                      const int* __restrict__ cols,
                                      const float* __restrict__ vals,
                                      float* __restrict__ stack_u,
                                      float* __restrict__ stack_i) {
    long long tid = (long long)blockIdx.x * blockDim.x + threadIdx.x;
    long long e  = tid >> 4;
    int lane = (int)(tid & 15);
    if (e >= (long long)EDGES) return;
    int b = (int)(e / E_N);
    int r = rows[e];
    int c = cols[e];
    float v = vals[e];
    const float4* irow = (const float4*)(item_emb + (long long)c * D_N);
    const float4* urow = (const float4*)(user_emb + (long long)r * D_N);
    float4 iv = irow[lane];
    float4 uv = urow[lane];
    float* du = stack_u + ((long long)b * U_N + r) * D_N + lane * 4;
    float* di = stack_i + ((long long)b * I_N + c) * D_N + lane * 4;
    atomicAdd(du + 0, v * iv.x);
    atomicAdd(du + 1, v * iv.y);
    atomicAdd(du + 2, v * iv.z);
    atomicAdd(du + 3, v * iv.w);
    atomicAdd(di + 0, v * uv.x);
    atomicAdd(di + 1, v * uv.y);
    atomicAdd(di + 2, v * uv.z);
    atomicAdd(di + 3, v * uv.w);
}

// ---------------------------------------------------------------------------
// Phase 2: per-row dense transform + sigmoid, in place (unchanged).
// ---------------------------------------------------------------------------
template <int NROWS>
__global__ __launch_bounds__(64) void transform_kernel(
        float* __restrict__ stack,
        const float* __restrict__ W,
        float* __restrict__ mean_out) {
    const int row = blockIdx.x;
    const int j   = threadIdx.x;

    __shared__ float xs[B_N][D_N];
#pragma unroll
    for (int b = 0; b < B_N; ++b)
        xs[b][j] = stack[((long long)b * NROWS + row) * D_N + j];
    __syncthreads();

    float acc[B_N] = {0.f, 0.f, 0.f, 0.f};
#pragma unroll 8
    for (int d = 0; d < D_N; ++d) {
        float w = W[d * D_N + j];
#pragma unroll
        for (int b = 0; b < B_N; ++b)
            acc[b] += xs[b][d] * w;
    }

    float m = 0.25f * (acc[0] + acc[1] + acc[2] + acc[3]);
#pragma unroll
    for (int b = 0; b < B_N; ++b)
        stack[((long long)b * NROWS + row) * D_N + j] =
            1.0f / (1.0f + __expf(-acc[b]));
    mean_out[(long long)row * D_N + j] = 1.0f / (1.0f + __expf(-m));
}

// ---------------------------------------------------------------------------
extern "C" void kernel_launch(void* const* d_in, const int* in_sizes, int n_in,
                              void* d_out, int out_size, void* d_ws, size_t ws_size,
                              hipStream_t stream) {
    const float* user_emb = (const float*)d_in[0];
    const float* item_emb = (const float*)d_in[1];
    const int*   rows     = (const int*)  d_in[2];
    const int*   cols     = (const int*)  d_in[3];
    const float* vals     = (const float*)d_in[4];
    const float* u_w      = (const float*)d_in[5];
    const float* i_w      = (const float*)d_in[6];

    float* out = (float*)d_out;
    float* user_mean = out;
    float* item_mean = out + (long long)U_N * D_N;
    float* stack_u   = item_mean + (long long)I_N * D_N;     // [B,U,D] out
    float* stack_i   = stack_u + (long long)B_N * U_N * D_N; // [B,I,D] out

    // Workspace layout (per-side arrays reused across the two rounds):
    int* cnt_sm = (int*)d_ws;                      // [8][CPAD_S]
    int* off_sm = cnt_sm + NSL * CPAD_S;           // [8][CPAD_S]
    int* cur_sm = off_sm + NSL * CPAD_S;           // [8][CPAD_S]
    int* off_ch = cur_sm + NSL * CPAD_S;           // [CPAD_S]
    int* cnt_ch = off_ch + CPAD_S;                 // [CPAD_S]
    int* binoff = cnt_ch + CPAD_S;                 // [NSC_U*32]
    int* flags  = binoff + NSC_U * G_BINS;         // [CPAD_S]
    int* bsum   = flags + CPAD_S;                  // [256]
    uint2* pay  = (uint2*)(bsum + 256);            // [EDGES] (64 MB)
    unsigned short* user16 = (unsigned short*)(pay + EDGES);
    unsigned short* item16 = user16 + (size_t)U_N * D_N;
    size_t needed = (size_t)(3 * NSL * CPAD_S + 3 * CPAD_S + NSC_U * G_BINS + 256) * 4
                  + (size_t)EDGES * 8 + (size_t)(U_N + I_N) * D_N * 2;  // ~86 MB

    if (ws_size >= needed) {
        int ncvt = (U_N + I_N) * D_N;
        cvt_kernel<<<(ncvt + 255) / 256, 256, 0, stream>>>(user_emb, item_emb,
                                                           user16, item16);
        // ---- Round A: user side (12,500 chunks; gathers item table) ----
        hipMemsetAsync(cnt_sm, 0, (size_t)NSL * CPAD_S * sizeof(int), stream);
        chist_kernel<<<NSL * 32, 256, 0, stream>>>(rows, cols, 0, 0, cnt_sm);
        scan_a<<<SCB_U, 256, 0, stream>>>(cnt_sm, NSC_U, bsum);
        scan_b<<<1, 256, 0, stream>>>(bsum, SCB_U);
        scan_c<<<SCB_U, 256, 0, stream>>>(cnt_sm, bsum, NSC_U, off_sm, cur_sm,
                                          off_ch, cnt_ch);
        cpart_kernel<<<NSL * CPB, 256, 0, stream>>>(rows, cols, vals, 0, 0,
                                                    cur_sm, pay);
        binsort_kernel<<<NSC_U, 256, 0, stream>>>(off_ch, cnt_ch, pay, binoff, flags);
        accum_kernel<<<NSC_U, 256, 0, stream>>>(item16, off_ch, cnt_ch, binoff,
                                                flags, pay, stack_u);
        // ---- Round B: item side (6,250 chunks; gathers user table) ----
        hipMemsetAsync(cnt_sm, 0, (size_t)NSL * CPAD_S * sizeof(int), stream);
        chist_kernel<<<NSL * 32, 256, 0, stream>>>(rows, cols, EDGES, NSC_U, cnt_sm);
        scan_a<<<SCB_I, 256, 0, stream>>>(cnt_sm, NSC_I, bsum);
        scan_b<<<1, 256, 0, stream>>>(bsum, SCB_I);
        scan_c<<<SCB_I, 256, 0, stream>>>(cnt_sm, bsum, NSC_I, off_sm, cur_sm,
                                          off_ch, cnt_ch);
        cpart_kernel<<<NSL * CPB, 256, 0, stream>>>(rows, cols, vals, EDGES, NSC_U,
                                                    cur_sm, pay);
        binsort_kernel<<<NSC_I, 256, 0, stream>>>(off_ch, cnt_ch, pay, binoff, flags);
        accum_kernel<<<NSC_I, 256, 0, stream>>>(user16, off_ch, cnt_ch, binoff,
                                                flags, pay, stack_i);
    } else {
        size_t stack_bytes = sizeof(float) * (size_t)B_N * (U_N + I_N) * D_N;
        hipMemsetAsync(stack_u, 0, stack_bytes, stream);
        long long nthreads = (long long)EDGES * 16;
        int nblocks = (int)((nthreads + 255) / 256);
        scatter_atomic_kernel<<<nblocks, 256, 0, stream>>>(
            user_emb, item_emb, rows, cols, vals, stack_u, stack_i);
    }

    transform_kernel<U_N><<<U_N, 64, 0, stream>>>(stack_u, u_w, user_mean);
    transform_kernel<I_N><<<I_N, 64, 0, stream>>>(stack_i, i_w, item_mean);
}

// Round 7
// 1187.194 us; speedup vs baseline: 6.8582x; 1.5361x over previous
//
#include <hip/hip_runtime.h>

#define U_N 100000
#define I_N 50000
#define D_N 64
#define B_N 4
#define E_N 2000000

#define EDGES   (B_N * E_N)            // 8,000,000 edge-entries per side
#define NSC_U   (U_N / 8)              // 12,500 chunks (8 rows x 4 behaviors)
#define NSC_I   (I_N / 8)              // 6,250 item chunks
#define CROW    12544                  // padded chunk-row length (>= NSC_U)
#define NBLK    256                    // partition blocks (32 per XCD)
#define EPB     (EDGES / NBLK)         // 31,250 entries per block (exact)
#define CAP     4096                   // fused-kernel LDS sort capacity
#define SC_T    13                     // 1024*13 >= 12,500

// Bin key: bin = row*4 + behavior  ->  chunk = row>>3 (8 rows x 4 behaviors),
// local = ((row&7)<<2) | b. Both sides iterate the same 8M edges; user side
// keys=rows / gathers item table; item side keys=cols / gathers user table.

// ---------------------------------------------------------------------------
// Pass 0: convert both embedding tables to bf16 (RNE). Halves gather bytes.
// ---------------------------------------------------------------------------
__global__ __launch_bounds__(256) void cvt_kernel(const float* __restrict__ ue,
                                                  const float* __restrict__ ie,
                                                  unsigned short* __restrict__ u16,
                                                  unsigned short* __restrict__ i16) {
    int i = blockIdx.x * 256 + threadIdx.x;
    int nu = U_N * D_N;
    int ni = I_N * D_N;
    if (i < nu) {
        unsigned u = __float_as_uint(ue[i]);
        u += 0x7FFFu + ((u >> 16) & 1u);
        u16[i] = (unsigned short)(u >> 16);
    } else if (i < nu + ni) {
        int j = i - nu;
        unsigned u = __float_as_uint(ie[j]);
        u += 0x7FFFu + ((u >> 16) & 1u);
        i16[j] = (unsigned short)(u >> 16);
    }
}

// ---------------------------------------------------------------------------
// Pass 1: per-(block, chunk) histogram. Block lb owns entries
// [lb*EPB, (lb+1)*EPB); LDS histogram over <=12,500 chunks; writes its count
// row coalesced. lb is XCD-major so scan order groups same-XCD blocks.
// ---------------------------------------------------------------------------
__global__ __launch_bounds__(512) void bhist_kernel(const int* __restrict__ keys,
                                                    int nsc,
                                                    int* __restrict__ cnt) {
    __shared__ int h[CROW];
    for (int i = threadIdx.x; i < nsc; i += 512) h[i] = 0;
    __syncthreads();
    int lb = ((blockIdx.x & 7) << 5) | (blockIdx.x >> 3);
    int base = lb * EPB;
    for (int i = threadIdx.x; i < EPB; i += 512)
        atomicAdd(&h[keys[base + i] >> 3], 1);
    __syncthreads();
    int* row = cnt + (size_t)lb * CROW;
    for (int i = threadIdx.x; i < nsc; i += 512) row[i] = h[i];
}

// ---------------------------------------------------------------------------
// Pass 2a: per-chunk totals.  2b: exclusive scan of totals.  2c: convert the
// per-(block,chunk) counts IN PLACE into per-block starting cursors
// (chunk-major, block-minor order -> chunk segments contiguous in pay).
// ---------------------------------------------------------------------------
__global__ __launch_bounds__(512) void scan_tot(const int* __restrict__ cnt,
                                                int nsc, int* __restrict__ cnt_ch) {
    int c = blockIdx.x * 512 + threadIdx.x;
    if (c >= nsc) return;
    int s = 0;
    for (int lb = 0; lb < NBLK; ++lb) s += cnt[(size_t)lb * CROW + c];
    cnt_ch[c] = s;
}

__global__ __launch_bounds__(1024) void scan_ex(const int* __restrict__ cnt_ch,
                                                int nsc, int* __restrict__ off_ch) {
    int t = threadIdx.x;
    int loc[SC_T]; int s = 0;
#pragma unroll
    for (int j = 0; j < SC_T; ++j) {
        int idx = t * SC_T + j;
        int c = (idx < nsc) ? cnt_ch[idx] : 0;
        loc[j] = s; s += c;
    }
    __shared__ int sm[1024];
    int mine = s; sm[t] = s; __syncthreads();
    for (int o = 1; o < 1024; o <<= 1) {
        int a = (t >= o) ? sm[t - o] : 0;
        __syncthreads(); sm[t] += a; __syncthreads();
    }
    int pre = sm[t] - mine;
#pragma unroll
    for (int j = 0; j < SC_T; ++j) {
        int idx = t * SC_T + j;
        if (idx < nsc) off_ch[idx] = pre + loc[j];
    }
}

__global__ __launch_bounds__(512) void scan_cur(int* __restrict__ cnt,
                                                const int* __restrict__ off_ch,
                                                int nsc) {
    int c = blockIdx.x * 512 + threadIdx.x;
    if (c >= nsc) return;
    int run = off_ch[c];
    for (int lb = 0; lb < NBLK; ++lb) {
        int v = cnt[(size_t)lb * CROW + c];
        cnt[(size_t)lb * CROW + c] = run;
        run += v;
    }
}

// ---------------------------------------------------------------------------
// Pass 3: placement. ZERO global atomics: block loads its private cursor row
// into LDS, bumps cursors with LDS atomics, stores payload at deterministic
// positions. Same-XCD blocks write adjacent sub-segments -> full-line L2
// writebacks. pay = { local(5b)<<17 | src(17b), v (f32) }.
// ---------------------------------------------------------------------------
__global__ __launch_bounds__(512) void cplace_kernel(const int* __restrict__ keys,
                                                     const int* __restrict__ srcs,
                                                     const float* __restrict__ vals,
                                                     const int* __restrict__ cur_g,
                                                     int nsc,
                                                     uint2* __restrict__ pay) {
    __shared__ int cur[CROW];
    int lb = ((blockIdx.x & 7) << 5) | (blockIdx.x >> 3);
    const int* row = cur_g + (size_t)lb * CROW;
    for (int i = threadIdx.x; i < nsc; i += 512) cur[i] = row[i];
    __syncthreads();
    int base = lb * EPB;
    int b = lb >> 6;                     // behavior: 64 blocks per behavior
    for (int i = threadIdx.x; i < EPB; i += 512) {
        int gi = base + i;
        int k = keys[gi];
        float v = vals[gi];
        int src = srcs[gi];
        int pos = atomicAdd(&cur[k >> 3], 1);
        pay[pos] = make_uint2(((unsigned)(((k & 7) << 2) | b) << 17) | (unsigned)src,
                              __float_as_uint(v));
    }
}

// ---------------------------------------------------------------------------
// Pass 4 (fused): per-chunk LDS counting-sort by local bin, register
// accumulation (wave w -> bins w*4..w*4+3, lane = dim), then the dense
// transform + sigmoid + behavior-mean, all in one kernel. A chunk holds all
// 4 behaviors of 8 rows, so the mean is block-local.
// ---------------------------------------------------------------------------
__global__ __launch_bounds__(512) void fused_kernel(
        const unsigned short* __restrict__ emb16,
        const float* __restrict__ W,
        const int* __restrict__ off_ch,
        const int* __restrict__ cnt_ch,
        const uint2* __restrict__ pay,
        float* __restrict__ embs,        // [B][nrows][64] <- sigmoid(x@W)
        float* __restrict__ mean_out,    // [nrows][64]    <- sigmoid(mean@W)
        int nrows) {
    int g = blockIdx.x;
    int start = off_ch[g], n = cnt_ch[g];
    int t = threadIdx.x, w = t >> 6, lane = t & 63;

    __shared__ uint2 st[CAP];            // 32 KB (reused as xs/ys after sort)
    __shared__ uint2 st2[CAP];           // 32 KB (sorted payload)
    __shared__ int c32[32];
    __shared__ int bstart[33];
    float* xs = (float*)st;              // [32][64] raw accumulators
    float* ys = ((float*)st) + 2048;     // [32][64] pre-sigmoid y

    if (n <= CAP) {
        if (t < 32) c32[t] = 0;
        __syncthreads();
        for (int i = t; i < n; i += 512) {
            uint2 p = pay[start + i];
            st[i] = p;
            atomicAdd(&c32[p.x >> 17], 1);
        }
        __syncthreads();
        if (t == 0) {
            int s = 0;
            for (int b2 = 0; b2 < 32; ++b2) {
                bstart[b2] = s; s += c32[b2]; c32[b2] = bstart[b2];
            }
            bstart[32] = s;
        }
        __syncthreads();
        for (int i = t; i < n; i += 512) {
            uint2 p = st[i];
            int pos = atomicAdd(&c32[p.x >> 17], 1);
            st2[pos] = p;
        }
        __syncthreads();
        // register accumulation; st free after this sync -> reuse as xs
        float acc[4];
#pragma unroll
        for (int q = 0; q < 4; ++q) {
            int b2 = w * 4 + q;
            int s0 = bstart[b2], s1 = bstart[b2 + 1];
            float a = 0.f;
#pragma unroll 4
            for (int j = s0; j < s1; ++j) {
                uint2 pv = st2[j];
                float x = __uint_as_float(
                    (unsigned)emb16[(pv.x & 0x1FFFFu) * 64 + lane] << 16);
                a = fmaf(__uint_as_float(pv.y), x, a);
            }
            acc[q] = a;
        }
#pragma unroll
        for (int q = 0; q < 4; ++q) xs[(w * 4 + q) * 64 + lane] = acc[q];
        // xs/ys deps below are intra-wave (group w reads only bins w*4..w*4+3)
    } else {
        // fallback (never for this input): unsorted LDS-atomic accumulate
        for (int i = t; i < 2048; i += 512) xs[i] = 0.f;
        __syncthreads();
        for (int j = w; j < n; j += 8) {
            uint2 pv = pay[start + j];
            float x = __uint_as_float(
                (unsigned)emb16[(pv.x & 0x1FFFFu) * 64 + lane] << 16);
            atomicAdd(&xs[(pv.x >> 17) * 64 + lane],
                      __uint_as_float(pv.y) * x);
        }
        __syncthreads();                 // cross-wave xs -> sync required
    }

    // transform: group w, bins w*4..w*4+3, output column j = lane
    float y[4] = {0.f, 0.f, 0.f, 0.f};
    for (int d = 0; d < 64; ++d) {
        float wv = W[d * 64 + lane];
#pragma unroll
        for (int q = 0; q < 4; ++q)
            y[q] = fmaf(xs[(w * 4 + q) * 64 + d], wv, y[q]);
    }
#pragma unroll
    for (int q = 0; q < 4; ++q) {
        int b2 = w * 4 + q;                  // row r = g*8 + w, behavior q
        ys[b2 * 64 + lane] = y[q];
        embs[((long long)(b2 & 3) * nrows + (g * 8 + (b2 >> 2))) * 64 + lane] =
            1.f / (1.f + __expf(-y[q]));
    }
    // mean over behaviors of row g*8+w: bins w*4..w*4+3 (intra-wave in ys)
    float m = 0.25f * (ys[(w * 4 + 0) * 64 + lane] + ys[(w * 4 + 1) * 64 + lane] +
                       ys[(w * 4 + 2) * 64 + lane] + ys[(w * 4 + 3) * 64 + lane]);
    mean_out[(long long)(g * 8 + w) * 64 + lane] = 1.f / (1.f + __expf(-m));
}

// ---------------------------------------------------------------------------
// Deep fallback: atomic scatter + separate transform (only if ws too small).
// ---------------------------------------------------------------------------
__global__ void scatter_atomic_kernel(const float* __restrict__ user_emb,
                                      const float* __restrict__ item_emb,
                                      const int* __restrict__ rows,
                                      const int* __restrict__ cols,
                                      const float* __restrict__ vals,
                                      float* __restrict__ stack_u,
                                      float* __restrict__ stack_i) {
    long long tid = (long long)blockIdx.x * blockDim.x + threadIdx.x;
    long long e  = tid >> 4;
    int lane = (int)(tid & 15);
    if (e >= (long long)EDGES) return;
    int b = (int)(e / E_N);
    int r = rows[e];
    int c = cols[e];
    float v = vals[e];
    const float4* irow = (const float4*)(item_emb + (long long)c * D_N);
    const float4* urow = (const float4*)(user_emb + (long long)r * D_N);
    float4 iv = irow[lane];
    float4 uv = urow[lane];
    float* du = stack_u + ((long long)b * U_N + r) * D_N + lane * 4;
    float* di = stack_i + ((long long)b * I_N + c) * D_N + lane * 4;
    atomicAdd(du + 0, v * iv.x);
    atomicAdd(du + 1, v * iv.y);
    atomicAdd(du + 2, v * iv.z);
    atomicAdd(du + 3, v * iv.w);
    atomicAdd(di + 0, v * uv.x);
    atomicAdd(di + 1, v * uv.y);
    atomicAdd(di + 2, v * uv.z);
    atomicAdd(di + 3, v * uv.w);
}

template <int NROWS>
__global__ __launch_bounds__(64) void transform_kernel(
        float* __restrict__ stack,
        const float* __restrict__ W,
        float* __restrict__ mean_out) {
    const int row = blockIdx.x;
    const int j   = threadIdx.x;
    __shared__ float xs[B_N][D_N];
#pragma unroll
    for (int b = 0; b < B_N; ++b)
        xs[b][j] = stack[((long long)b * NROWS + row) * D_N + j];
    __syncthreads();
    float acc[B_N] = {0.f, 0.f, 0.f, 0.f};
#pragma unroll 8
    for (int d = 0; d < D_N; ++d) {
        float w = W[d * D_N + j];
#pragma unroll
        for (int b = 0; b < B_N; ++b)
            acc[b] += xs[b][d] * w;
    }
    float m = 0.25f * (acc[0] + acc[1] + acc[2] + acc[3]);
#pragma unroll
    for (int b = 0; b < B_N; ++b)
        stack[((long long)b * NROWS + row) * D_N + j] =
            1.0f / (1.0f + __expf(-acc[b]));
    mean_out[(long long)row * D_N + j] = 1.0f / (1.0f + __expf(-m));
}

// ---------------------------------------------------------------------------
extern "C" void kernel_launch(void* const* d_in, const int* in_sizes, int n_in,
                              void* d_out, int out_size, void* d_ws, size_t ws_size,
                              hipStream_t stream) {
    const float* user_emb = (const float*)d_in[0];
    const float* item_emb = (const float*)d_in[1];
    const int*   rows     = (const int*)  d_in[2];
    const int*   cols     = (const int*)  d_in[3];
    const float* vals     = (const float*)d_in[4];
    const float* u_w      = (const float*)d_in[5];
    const float* i_w      = (const float*)d_in[6];

    float* out = (float*)d_out;
    float* user_mean = out;
    float* item_mean = out + (long long)U_N * D_N;
    float* stack_u   = item_mean + (long long)I_N * D_N;     // user_embs out
    float* stack_i   = stack_u + (long long)B_N * U_N * D_N; // item_embs out

    // Workspace: cnt [NBLK][CROW] | cnt_ch | off_ch | pay [EDGES] | bf16 tables
    int* cnt    = (int*)d_ws;
    int* cnt_ch = cnt + (size_t)NBLK * CROW;
    int* off_ch = cnt_ch + CROW;
    uint2* pay  = (uint2*)(off_ch + CROW);
    unsigned short* user16 = (unsigned short*)(pay + EDGES);
    unsigned short* item16 = user16 + (size_t)U_N * D_N;
    size_t needed = ((size_t)NBLK * CROW + 2 * CROW) * 4 +
                    (size_t)EDGES * 8 + (size_t)(U_N + I_N) * D_N * 2; // ~96 MB

    if (ws_size >= needed) {
        int ncvt = (U_N + I_N) * D_N;
        cvt_kernel<<<(ncvt + 255) / 256, 256, 0, stream>>>(user_emb, item_emb,
                                                           user16, item16);
        // ---- user side: keys=rows, gathers item table ----
        bhist_kernel<<<NBLK, 512, 0, stream>>>(rows, NSC_U, cnt);
        scan_tot<<<(NSC_U + 511) / 512, 512, 0, stream>>>(cnt, NSC_U, cnt_ch);
        scan_ex<<<1, 1024, 0, stream>>>(cnt_ch, NSC_U, off_ch);
        scan_cur<<<(NSC_U + 511) / 512, 512, 0, stream>>>(cnt, off_ch, NSC_U);
        cplace_kernel<<<NBLK, 512, 0, stream>>>(rows, cols, vals, cnt, NSC_U, pay);
        fused_kernel<<<NSC_U, 512, 0, stream>>>(item16, u_w, off_ch, cnt_ch, pay,
                                                stack_u, user_mean, U_N);
        // ---- item side: keys=cols, gathers user table ----
        bhist_kernel<<<NBLK, 512, 0, stream>>>(cols, NSC_I, cnt);
        scan_tot<<<(NSC_I + 511) / 512, 512, 0, stream>>>(cnt, NSC_I, cnt_ch);
        scan_ex<<<1, 1024, 0, stream>>>(cnt_ch, NSC_I, off_ch);
        scan_cur<<<(NSC_I + 511) / 512, 512, 0, stream>>>(cnt, off_ch, NSC_I);
        cplace_kernel<<<NBLK, 512, 0, stream>>>(cols, rows, vals, cnt, NSC_I, pay);
        fused_kernel<<<NSC_I, 512, 0, stream>>>(user16, i_w, off_ch, cnt_ch, pay,
                                                stack_i, item_mean, I_N);
    } else {
        size_t stack_bytes = sizeof(float) * (size_t)B_N * (U_N + I_N) * D_N;
        hipMemsetAsync(stack_u, 0, stack_bytes, stream);
        long long nthreads = (long long)EDGES * 16;
        int nblocks = (int)((nthreads + 255) / 256);
        scatter_atomic_kernel<<<nblocks, 256, 0, stream>>>(
            user_emb, item_emb, rows, cols, vals, stack_u, stack_i);
        transform_kernel<U_N><<<U_N, 64, 0, stream>>>(stack_u, u_w, user_mean);
        transform_kernel<I_N><<<I_N, 64, 0, stream>>>(stack_i, i_w, item_mean);
    }
}